// Round 2
// baseline (9313.994 us; speedup 1.0000x reference)
//
#include <hip/hip_runtime.h>

// RVQ fused kernel v2, f32, LDS-instruction-minimized.
// x: [16,4096,256] f32 -> N=65536 rows, D=256
// emb: [8,1024,256] f32
// out: [quantized 16777216][loss 1][indices-as-float 524288]
// ws:  [e2 8192 f32][lossPart 2048 f32]

#define NROWS   65536
#define DDIM    256
#define KCODES  1024
#define QSTAGES 8
#define BR      32     // rows per block
#define RS      36     // res LDS row stride (36%4==0 for b128 alignment)

__global__ void e2_kernel(const float* __restrict__ emb, float* __restrict__ e2) {
  const int row  = blockIdx.x * 4 + (threadIdx.x >> 6);
  const int lane = threadIdx.x & 63;
  const float4 v = ((const float4*)(emb + (size_t)row * DDIM))[lane];
  float s = v.x * v.x + v.y * v.y + v.z * v.z + v.w * v.w;
  #pragma unroll
  for (int m = 32; m >= 1; m >>= 1) s += __shfl_xor(s, m);
  if (lane == 0) e2[row] = s;
}

__global__ __launch_bounds__(256, 2)
void rvq_kernel(const float* __restrict__ x, const float* __restrict__ emb,
                const float* __restrict__ e2g, float* __restrict__ out,
                float* __restrict__ outIdx, float* __restrict__ lossPart)
{
  __shared__ __align__(16) float res[DDIM][RS];   // 36.9 KB residual, [d][row]
  __shared__ __align__(16) float et[8][KCODES];   // 32 KB code chunk, [d][code]
  __shared__ int   sidx[BR];
  __shared__ float red[4];

  const int tid = threadIdx.x;
  const int wv  = tid >> 6;   // wave id 0..3 -> row group (rows 8*wv..8*wv+7)
  const int ln  = tid & 63;   // lane -> code group (cols 4*ln + 256*q)
  const int ur  = tid & 31;   // update phase: row
  const int uq  = tid >> 5;   // update phase: d-chunk 0..7
  const size_t rowBase = (size_t)blockIdx.x * BR;
  const float* xrow = x + (rowBase + ur) * DDIM;

  // ---- load x tile -> res (transposed [d][row]); 2-way bank pattern ----
  #pragma unroll
  for (int f = 0; f < 8; ++f) {
    const int d0 = uq * 32 + 4 * f;
    const float4 v = *(const float4*)(xrow + d0);
    res[d0 + 0][ur] = v.x; res[d0 + 1][ur] = v.y;
    res[d0 + 2][ur] = v.z; res[d0 + 3][ur] = v.w;
  }

  float lossAcc = 0.f;
  const size_t codeOff = (size_t)(4 * tid) * DDIM;  // this thread's 4 staged codes
  float pf[4][8];                                   // prefetch regs (static idx only)
  {
    const float* eb = emb + codeOff;                // stage 0, chunk 0
    #pragma unroll
    for (int j = 0; j < 4; ++j)
      #pragma unroll
      for (int dd = 0; dd < 8; ++dd)
        pf[j][dd] = eb[j * DDIM + dd];
  }

  for (int qi = 0; qi < QSTAGES; ++qi) {
    const float* embq = emb + (size_t)qi * (KCODES * DDIM);
    float acc[8][16];
    #pragma unroll
    for (int i = 0; i < 8; ++i)
      #pragma unroll
      for (int j = 0; j < 16; ++j) acc[i][j] = 0.f;

    for (int ch = 0; ch < 32; ++ch) {
      __syncthreads();                 // prior compute done reading et (+ res update ordering)
      // vectorized transpose-write: lane-contiguous b128, conflict-free
      #pragma unroll
      for (int dd = 0; dd < 8; ++dd)
        *(float4*)&et[dd][4 * tid] =
            make_float4(pf[0][dd], pf[1][dd], pf[2][dd], pf[3][dd]);
      // issue next chunk's gather loads early (hidden under compute below)
      const int s = qi * 32 + ch + 1;
      if (s < 256) {
        const float* eb = emb + (size_t)(s >> 5) * (KCODES * DDIM) + (s & 31) * 8 + codeOff;
        #pragma unroll
        for (int j = 0; j < 4; ++j)
          #pragma unroll
          for (int dd = 0; dd < 8; ++dd)
            pf[j][dd] = eb[j * DDIM + dd];
      }
      __syncthreads();                 // et ready
      #pragma unroll
      for (int dd = 0; dd < 8; ++dd) {
        const int d = ch * 8 + dd;
        const float4 ra = *(const float4*)&res[d][8 * wv];      // wave-uniform broadcast
        const float4 rb = *(const float4*)&res[d][8 * wv + 4];
        const float rv[8] = {ra.x, ra.y, ra.z, ra.w, rb.x, rb.y, rb.z, rb.w};
        float ev[16];
        #pragma unroll
        for (int q = 0; q < 4; ++q) {
          const float4 e4 = *(const float4*)&et[dd][4 * ln + 256 * q];  // contiguous
          ev[4 * q + 0] = e4.x; ev[4 * q + 1] = e4.y;
          ev[4 * q + 2] = e4.z; ev[4 * q + 3] = e4.w;
        }
        #pragma unroll
        for (int i = 0; i < 8; ++i)
          #pragma unroll
          for (int j = 0; j < 16; ++j)
            acc[i][j] += rv[i] * ev[j];
      }
    }

    // ---- scoring + argmin (regs only; full K done) ----
    float bestV[8]; int bestI[8];
    #pragma unroll
    for (int i = 0; i < 8; ++i) { bestV[i] = 3.4e38f; bestI[i] = 0; }
    const float* e2q = e2g + qi * KCODES;
    #pragma unroll
    for (int q = 0; q < 4; ++q) {
      const float4 e4 = *(const float4*)(e2q + 4 * ln + 256 * q);
      const float ee[4] = {e4.x, e4.y, e4.z, e4.w};
      #pragma unroll
      for (int jj = 0; jj < 4; ++jj) {
        const int col = 4 * ln + 256 * q + jj;     // ascending scan -> lowest idx on tie
        #pragma unroll
        for (int i = 0; i < 8; ++i) {
          const float v = ee[jj] - 2.f * acc[i][4 * q + jj];
          if (v < bestV[i]) { bestV[i] = v; bestI[i] = col; }
        }
      }
    }
    #pragma unroll
    for (int m = 1; m <= 32; m <<= 1) {            // 64-lane lexicographic min
      #pragma unroll
      for (int i = 0; i < 8; ++i) {
        const float ov = __shfl_xor(bestV[i], m);
        const int   oi = __shfl_xor(bestI[i], m);
        if (ov < bestV[i] || (ov == bestV[i] && oi < bestI[i])) {
          bestV[i] = ov; bestI[i] = oi;
        }
      }
    }
    if (ln == 0) {
      #pragma unroll
      for (int i = 0; i < 8; ++i) sidx[8 * wv + i] = bestI[i];
    }
    __syncthreads();   // sidx visible AND all waves done reading res in last chunk

    // ---- residual update + loss; 8 threads/row, 2-way-free bank pattern ----
    {
      const int code = sidx[ur];
      const float* eg = embq + (size_t)code * DDIM;
      float ls = 0.f;
      #pragma unroll
      for (int f = 0; f < 8; ++f) {
        const int d0 = uq * 32 + 4 * f;
        const float4 ev4 = *(const float4*)(eg + d0);
        float a;
        a = res[d0 + 0][ur] - ev4.x; res[d0 + 0][ur] = a; ls += a * a;
        a = res[d0 + 1][ur] - ev4.y; res[d0 + 1][ur] = a; ls += a * a;
        a = res[d0 + 2][ur] - ev4.z; res[d0 + 2][ur] = a; ls += a * a;
        a = res[d0 + 3][ur] - ev4.w; res[d0 + 3][ur] = a; ls += a * a;
      }
      lossAcc += ls;
    }
    if (tid < BR) outIdx[(rowBase + tid) * QSTAGES + qi] = (float)sidx[tid];
    // next chunk-0 double-sync orders these res writes vs next stage's reads
  }
  __syncthreads();   // all updates done before reading res for final out

  // ---- quantized output: out = x - res_final ----
  #pragma unroll
  for (int f = 0; f < 8; ++f) {
    const int d0 = uq * 32 + 4 * f;
    const float4 xv = *(const float4*)(xrow + d0);
    float4 o;
    o.x = xv.x - res[d0 + 0][ur];
    o.y = xv.y - res[d0 + 1][ur];
    o.z = xv.z - res[d0 + 2][ur];
    o.w = xv.w - res[d0 + 3][ur];
    *(float4*)(out + (rowBase + ur) * DDIM + d0) = o;
  }

  // ---- deterministic per-block loss partial ----
  float sr = lossAcc;
  #pragma unroll
  for (int m = 32; m >= 1; m >>= 1) sr += __shfl_xor(sr, m);
  if ((tid & 63) == 0) red[tid >> 6] = sr;
  __syncthreads();
  if (tid == 0) lossPart[blockIdx.x] = red[0] + red[1] + red[2] + red[3];
}

__global__ void loss_final(const float* __restrict__ part, float* __restrict__ outLoss) {
  __shared__ float buf[256];
  const int t = threadIdx.x;
  float s = 0.f;
  #pragma unroll
  for (int k = 0; k < 8; ++k) s += part[t + 256 * k];
  buf[t] = s;
  __syncthreads();
  for (int st = 128; st >= 1; st >>= 1) {
    if (t < st) buf[t] += buf[t + st];
    __syncthreads();
  }
  if (t == 0) *outLoss = buf[0] * (1.25f / 16777216.f);
}

extern "C" void kernel_launch(void* const* d_in, const int* in_sizes, int n_in,
                              void* d_out, int out_size, void* d_ws, size_t ws_size,
                              hipStream_t stream) {
  (void)in_sizes; (void)n_in; (void)out_size; (void)ws_size;
  const float* x   = (const float*)d_in[0];
  const float* emb = (const float*)d_in[1];
  float* out     = (float*)d_out;
  float* outLoss = out + (size_t)NROWS * DDIM;          // 16777216
  float* outIdx  = outLoss + 1;                         // indices as float
  float* e2      = (float*)d_ws;                        // 8192 floats
  float* part    = e2 + QSTAGES * KCODES;               // 2048 floats

  e2_kernel<<<dim3(QSTAGES * KCODES / 4), dim3(256), 0, stream>>>(emb, e2);
  rvq_kernel<<<dim3(NROWS / BR), dim3(256), 0, stream>>>(x, emb, e2, out, outIdx, part);
  loss_final<<<dim3(1), dim3(256), 0, stream>>>(part, outLoss);
}

// Round 3
// 984.187 us; speedup vs baseline: 9.4636x; 9.4636x over previous
//
#include <hip/hip_runtime.h>

// RVQ v3: bf16 split-GEMM on MFMA + guaranteed-margin exact rescue.
// x: [16,4096,256] f32 ; emb: [8,1024,256] f32
// out: [quantized 16777216][loss 1][indices-as-float 524288]
// ws:  [packE 4MB bf16][e2 8192 f32][lossPart 1024 f32]

#define NROWS 65536
#define DDIM  256
#define KC    1024
#define QST   8
#define BR    64
#define MCAP  24

typedef __attribute__((ext_vector_type(8))) short short8;
typedef __attribute__((ext_vector_type(4))) float f32x4;
typedef unsigned int u32;
typedef unsigned short u16;

__device__ __forceinline__ u16 f2bf(float f) {
  u32 b = __float_as_uint(f);
  return (u16)((b + 0x7FFFu + ((b >> 16) & 1u)) >> 16);
}
__device__ __forceinline__ float bf2f(u16 h) {
  return __uint_as_float(((u32)h) << 16);
}
// byte offset of 16B unit u (0..63) of row's split-residual, XOR-swizzled
__device__ __forceinline__ u32 runit(int row, int u) {
  return (u32)(row * 1024 + ((u ^ (row & 7)) << 4));
}
__device__ __forceinline__ void gld16(const void* g, void* lds) {
  __builtin_amdgcn_global_load_lds((const __attribute__((address_space(1))) u32*)g,
                                   (__attribute__((address_space(3))) u32*)lds, 16, 0, 0);
}

__global__ void e2_kernel(const float* __restrict__ emb, float* __restrict__ e2) {
  const int row  = blockIdx.x * 4 + (threadIdx.x >> 6);
  const int lane = threadIdx.x & 63;
  const float4 v = ((const float4*)(emb + (size_t)row * DDIM))[lane];
  float s = v.x * v.x + v.y * v.y + v.z * v.z + v.w * v.w;
  #pragma unroll
  for (int m = 32; m >= 1; m >>= 1) s += __shfl_xor(s, m);
  if (lane == 0) e2[row] = s;
}

// Pack eh (bf16 of emb) into the exact A-frag stream order:
// slot t = (((qi*16+ct)*8+ekt)*4+ci)*64 + l ; 8 bf16 each:
//   emb[qi][ct*64+ci*16+(l&15)][ekt*32+(l>>4)*8 + j]
__global__ void pack_kernel(const float* __restrict__ emb, u16* __restrict__ packE) {
  const int t = blockIdx.x * 256 + threadIdx.x;   // 262144 slots
  const int l   = t & 63;
  const int ci  = (t >> 6) & 3;
  const int ekt = (t >> 8) & 7;
  const int ct  = (t >> 11) & 15;
  const int qi  = t >> 15;
  const int code = ct * 64 + ci * 16 + (l & 15);
  const int d0   = ekt * 32 + (l >> 4) * 8;
  const float* src = emb + ((size_t)qi * KC + code) * DDIM + d0;
  short8 v;
  #pragma unroll
  for (int j = 0; j < 8; ++j) v[j] = (short)f2bf(src[j]);
  *(short8*)(packE + (size_t)t * 8) = v;
}

__global__ __launch_bounds__(512, 2)
void rvq_kernel(const float* __restrict__ x, const float* __restrict__ emb,
                const char* __restrict__ packEb, const float* __restrict__ e2g,
                float* __restrict__ out, float* __restrict__ outIdx,
                float* __restrict__ lossPart)
{
  __shared__ __align__(16) u16  Rl[BR * 512];       // 64KB split residual (swizzled)
  __shared__ __align__(16) char Bbuf[8][2][4096];   // 64KB per-wave E staging (dbuf)
  __shared__ float e2L[KC];                         // 4KB
  __shared__ float sredV[8][BR];
  __shared__ int   sredI[8][BR];
  __shared__ float d0L[BR];
  __shared__ int   cntL[BR];
  __shared__ int   candL[BR][MCAP];
  __shared__ int   sidx[BR];
  __shared__ float rnormL[BR];
  __shared__ float redbuf[8];

  const int tid = threadIdx.x;
  const int w = tid >> 6, l = tid & 63;
  const int g = l >> 4, rb16 = l & 15;
  const int row = tid >> 3, sub = tid & 7;        // update/rescue partition
  const size_t rowBase = (size_t)blockIdx.x * BR;
  char* RlB = (char*)Rl;
  float lossAcc = 0.f;
  float r[32];                                    // f32 residual, d = 32*sub + i

  // ---- init: r = x ; write bf16 split to LDS ; rnorm ----
  {
    const float* xp = x + (rowBase + row) * DDIM + 32 * sub;
    float rn = 0.f;
    #pragma unroll
    for (int uu = 0; uu < 4; ++uu) {
      f32x4 va = *(const f32x4*)(xp + 8 * uu);
      f32x4 vb = *(const f32x4*)(xp + 8 * uu + 4);
      r[8*uu+0]=va.x; r[8*uu+1]=va.y; r[8*uu+2]=va.z; r[8*uu+3]=va.w;
      r[8*uu+4]=vb.x; r[8*uu+5]=vb.y; r[8*uu+6]=vb.z; r[8*uu+7]=vb.w;
      short8 hv, lv;
      #pragma unroll
      for (int j = 0; j < 8; ++j) {
        float v = r[8*uu+j];
        u16 h = f2bf(v); float hf = bf2f(h);
        hv[j] = (short)h; lv[j] = (short)f2bf(v - hf);
        rn += v * v;
      }
      *(short8*)(RlB + runit(row, 4*sub + uu))      = hv;
      *(short8*)(RlB + runit(row, 32 + 4*sub + uu)) = lv;
    }
    rn += __shfl_xor(rn, 1); rn += __shfl_xor(rn, 2); rn += __shfl_xor(rn, 4);
    if (sub == 0) rnormL[row] = rn;
  }
  __syncthreads();

  for (int qi = 0; qi < QST; ++qi) {
    // ---- phase A: stage e2 into LDS ----
    e2L[tid]       = e2g[qi * KC + tid];
    e2L[tid + 512] = e2g[qi * KC + 512 + tid];
    __syncthreads();

    // ---- phase B: GEMM (barrier-free; per-wave counted-vmcnt pipeline) ----
    f32x4 acc[2][4][4];
    #pragma unroll
    for (int a = 0; a < 2; ++a)
      #pragma unroll
      for (int b = 0; b < 4; ++b)
        #pragma unroll
        for (int c2 = 0; c2 < 4; ++c2)
          acc[a][b][c2] = (f32x4){0.f, 0.f, 0.f, 0.f};

    const size_t stageBase = ((size_t)qi * 16 + 2 * w) * 8 * 4096;  // wave's ct pair
    #define CHUNK_SRC(c) (packEb + stageBase + (size_t)(c) * 4096 + (size_t)l * 16)
    #define ISSUE(c) do { \
      const char* _g = CHUNK_SRC(c); \
      char* _d = &Bbuf[w][(c) & 1][0]; \
      gld16(_g,        _d);        gld16(_g + 1024, _d + 1024); \
      gld16(_g + 2048, _d + 2048); gld16(_g + 3072, _d + 3072); \
    } while (0)

    ISSUE(0);
    #pragma unroll
    for (int c = 0; c < 16; ++c) {
      if (c < 15) { ISSUE(c + 1); asm volatile("s_waitcnt vmcnt(4)" ::: "memory"); }
      else        {               asm volatile("s_waitcnt vmcnt(0)" ::: "memory"); }
      const char* bufc = &Bbuf[w][c & 1][0];
      const int ekt = c & 7, ctl = c >> 3;
      short8 Af[4];
      #pragma unroll
      for (int ci = 0; ci < 4; ++ci)
        Af[ci] = *(const short8*)(bufc + ci * 1024 + l * 16);
      #pragma unroll
      for (int ri = 0; ri < 4; ++ri) {            // rh k-block
        short8 B = *(const short8*)(RlB + runit(16 * ri + rb16, ekt * 4 + g));
        #pragma unroll
        for (int ci = 0; ci < 4; ++ci)
          acc[ctl][ci][ri] = __builtin_amdgcn_mfma_f32_16x16x32_bf16(Af[ci], B, acc[ctl][ci][ri], 0, 0, 0);
      }
      #pragma unroll
      for (int ri = 0; ri < 4; ++ri) {            // rl k-block (same E chunk)
        short8 B = *(const short8*)(RlB + runit(16 * ri + rb16, 32 + ekt * 4 + g));
        #pragma unroll
        for (int ci = 0; ci < 4; ++ci)
          acc[ctl][ci][ri] = __builtin_amdgcn_mfma_f32_16x16x32_bf16(Af[ci], B, acc[ctl][ci][ri], 0, 0, 0);
      }
    }

    // ---- scoring + wave-local argmin (codes ascend: ctl, ci, j; cross-g via shfl) ----
    float bestV[4]; int bestI[4];
    #pragma unroll
    for (int ri = 0; ri < 4; ++ri) { bestV[ri] = 3.4e38f; bestI[ri] = 0; }
    #pragma unroll
    for (int ctl = 0; ctl < 2; ++ctl) {
      const int cb = (2 * w + ctl) * 64;
      #pragma unroll
      for (int ci = 0; ci < 4; ++ci) {
        f32x4 e4 = *(const f32x4*)&e2L[cb + 16 * ci + 4 * g];
        #pragma unroll
        for (int j = 0; j < 4; ++j) {
          const int code = cb + 16 * ci + 4 * g + j;
          #pragma unroll
          for (int ri = 0; ri < 4; ++ri) {
            float d = e4[j] - 2.f * acc[ctl][ci][ri][j];
            if (d < bestV[ri]) { bestV[ri] = d; bestI[ri] = code; }
          }
        }
      }
    }
    #pragma unroll
    for (int m = 16; m <= 32; m <<= 1) {
      #pragma unroll
      for (int ri = 0; ri < 4; ++ri) {
        float ov = __shfl_xor(bestV[ri], m);
        int   oi = __shfl_xor(bestI[ri], m);
        if (ov < bestV[ri] || (ov == bestV[ri] && oi < bestI[ri])) { bestV[ri] = ov; bestI[ri] = oi; }
      }
    }
    if (l < 16) {
      #pragma unroll
      for (int ri = 0; ri < 4; ++ri) { sredV[w][16*ri + l] = bestV[ri]; sredI[w][16*ri + l] = bestI[ri]; }
    }
    __syncthreads();

    // ---- phase D: cross-wave min, provisional idx, reset counters ----
    if (tid < BR) {
      float dv = sredV[0][tid]; int di = sredI[0][tid];
      #pragma unroll
      for (int wv = 1; wv < 8; ++wv) {
        float v = sredV[wv][tid]; int ii = sredI[wv][tid];
        if (v < dv || (v == dv && ii < di)) { dv = v; di = ii; }
      }
      d0L[tid] = dv; sidx[tid] = di; cntL[tid] = 0;
    }
    __syncthreads();

    // ---- phase E: candidates within guaranteed margin ----
    {
      float thr[4];
      #pragma unroll
      for (int ri = 0; ri < 4; ++ri) {
        const int rw = 16 * ri + rb16;
        thr[ri] = d0L[rw] + 0.36f * sqrtf(rnormL[rw]) + 0.05f;
      }
      #pragma unroll
      for (int ctl = 0; ctl < 2; ++ctl) {
        const int cb = (2 * w + ctl) * 64;
        #pragma unroll
        for (int ci = 0; ci < 4; ++ci) {
          f32x4 e4 = *(const f32x4*)&e2L[cb + 16 * ci + 4 * g];
          #pragma unroll
          for (int ri = 0; ri < 4; ++ri) {
            #pragma unroll
            for (int j = 0; j < 4; ++j) {
              float d = e4[j] - 2.f * acc[ctl][ci][ri][j];
              if (d <= thr[ri]) {
                const int rw = 16 * ri + rb16;
                int p = atomicAdd(&cntL[rw], 1);
                if (p < MCAP) candL[rw][p] = cb + 16 * ci + 4 * g + j;
              }
            }
          }
        }
      }
    }
    __syncthreads();

    // ---- phase F: exact f32 rescue for contested rows ----
    {
      int cnt = cntL[row];
      if (cnt > 1) {
        if (cnt > MCAP) cnt = MCAP;
        float bd = 3.4e38f; int bi = 0x7fffffff;
        for (int k2 = 0; k2 < cnt; ++k2) {
          const int c = candL[row][k2];
          const float* ep = emb + ((size_t)qi * KC + c) * DDIM + 32 * sub;
          float dot = 0.f;
          #pragma unroll
          for (int f = 0; f < 8; ++f) {
            f32x4 ev = *(const f32x4*)(ep + 4 * f);
            dot += r[4*f+0]*ev.x + r[4*f+1]*ev.y + r[4*f+2]*ev.z + r[4*f+3]*ev.w;
          }
          dot += __shfl_xor(dot, 1); dot += __shfl_xor(dot, 2); dot += __shfl_xor(dot, 4);
          float d = e2L[c] - 2.f * dot;
          if (d < bd || (d == bd && c < bi)) { bd = d; bi = c; }
        }
        if (sub == 0) sidx[row] = bi;
      }
    }
    __syncthreads();

    // ---- phase G: residual update (f32 regs), re-split to LDS, loss, indices ----
    {
      const int c = sidx[row];
      const float* ep = emb + ((size_t)qi * KC + c) * DDIM + 32 * sub;
      float ls = 0.f;
      #pragma unroll
      for (int f = 0; f < 8; ++f) {
        f32x4 ev = *(const f32x4*)(ep + 4 * f);
        r[4*f+0] -= ev.x; ls += r[4*f+0]*r[4*f+0];
        r[4*f+1] -= ev.y; ls += r[4*f+1]*r[4*f+1];
        r[4*f+2] -= ev.z; ls += r[4*f+2]*r[4*f+2];
        r[4*f+3] -= ev.w; ls += r[4*f+3]*r[4*f+3];
      }
      #pragma unroll
      for (int uu = 0; uu < 4; ++uu) {
        short8 hv, lv;
        #pragma unroll
        for (int j = 0; j < 8; ++j) {
          float v = r[8*uu+j];
          u16 h = f2bf(v); float hf = bf2f(h);
          hv[j] = (short)h; lv[j] = (short)f2bf(v - hf);
        }
        *(short8*)(RlB + runit(row, 4*sub + uu))      = hv;
        *(short8*)(RlB + runit(row, 32 + 4*sub + uu)) = lv;
      }
      float rn = ls;
      rn += __shfl_xor(rn, 1); rn += __shfl_xor(rn, 2); rn += __shfl_xor(rn, 4);
      if (sub == 0) rnormL[row] = rn;
      lossAcc += ls;
      if (tid < BR) outIdx[(rowBase + tid) * QST + qi] = (float)sidx[tid];
    }
    __syncthreads();
  }

  // ---- final: out = x - r_final (exact f32 regs) ----
  {
    const float* xp = x + (rowBase + row) * DDIM + 32 * sub;
    float* op = out + (rowBase + row) * DDIM + 32 * sub;
    #pragma unroll
    for (int f = 0; f < 8; ++f) {
      f32x4 xv = *(const f32x4*)(xp + 4 * f);
      f32x4 o;
      o.x = xv.x - r[4*f+0]; o.y = xv.y - r[4*f+1];
      o.z = xv.z - r[4*f+2]; o.w = xv.w - r[4*f+3];
      *(f32x4*)(op + 4 * f) = o;
    }
  }

  // ---- deterministic per-block loss partial ----
  {
    float s = lossAcc;
    #pragma unroll
    for (int m = 32; m >= 1; m >>= 1) s += __shfl_xor(s, m);
    if (l == 0) redbuf[w] = s;
    __syncthreads();
    if (tid == 0) {
      float t2 = 0.f;
      #pragma unroll
      for (int wv = 0; wv < 8; ++wv) t2 += redbuf[wv];
      lossPart[blockIdx.x] = t2;
    }
  }
}

__global__ void loss_final(const float* __restrict__ part, float* __restrict__ outLoss) {
  __shared__ float buf[256];
  const int t = threadIdx.x;
  float s = 0.f;
  #pragma unroll
  for (int k = 0; k < 4; ++k) s += part[t + 256 * k];
  buf[t] = s;
  __syncthreads();
  for (int st = 128; st >= 1; st >>= 1) {
    if (t < st) buf[t] += buf[t + st];
    __syncthreads();
  }
  if (t == 0) *outLoss = buf[0] * (1.25f / 16777216.f);
}

extern "C" void kernel_launch(void* const* d_in, const int* in_sizes, int n_in,
                              void* d_out, int out_size, void* d_ws, size_t ws_size,
                              hipStream_t stream) {
  (void)in_sizes; (void)n_in; (void)out_size; (void)ws_size;
  const float* x   = (const float*)d_in[0];
  const float* emb = (const float*)d_in[1];
  float* out     = (float*)d_out;
  float* outLoss = out + (size_t)NROWS * DDIM;            // 16777216
  float* outIdx  = outLoss + 1;                           // indices as float
  char*  packE   = (char*)d_ws;                           // 4 MB bf16 A-frag stream
  float* e2      = (float*)(packE + (size_t)QST*16*8*4*4096);  // 8192 f32
  float* part    = e2 + QST * KC;                         // 1024 f32

  pack_kernel<<<dim3(1024), dim3(256), 0, stream>>>(emb, (u16*)packE);
  e2_kernel<<<dim3(QST * KC / 4), dim3(256), 0, stream>>>(emb, e2);
  rvq_kernel<<<dim3(NROWS / BR), dim3(512), 0, stream>>>(x, emb, packE, e2, out, outIdx, part);
  loss_final<<<dim3(1), dim3(256), 0, stream>>>(part, outLoss);
}

// Round 4
// 877.196 us; speedup vs baseline: 10.6179x; 1.1220x over previous
//
#include <hip/hip_runtime.h>

// RVQ v4: rh-only bf16 GEMM (K=256) + guaranteed-margin exact rescue.
// 16-wave blocks, BR=64, acc=64 f32/lane, forced <=128 VGPR.
// x: [16,4096,256] f32 ; emb: [8,1024,256] f32
// out: [quantized 16777216][loss 1][indices-as-float 524288]
// ws:  [packE 4MB bf16][e2 8192 f32][lossPart 1024 f32]

#define NROWS 65536
#define DDIM  256
#define KC    1024
#define QST   8
#define BR    64
#define MCAP  24

typedef __attribute__((ext_vector_type(8))) short short8;
typedef __attribute__((ext_vector_type(4))) float f32x4;
typedef unsigned int u32;
typedef unsigned short u16;

__device__ __forceinline__ u16 f2bf(float f) {
  u32 b = __float_as_uint(f);
  return (u16)((b + 0x7FFFu + ((b >> 16) & 1u)) >> 16);
}
// byte offset of 16B unit u (0..31) of row's rh, XOR-swizzled (rows are 512B)
__device__ __forceinline__ u32 runit(int row, int u) {
  return (u32)(row * 512 + ((u ^ (row & 7)) << 4));
}
__device__ __forceinline__ void gld16(const void* g, void* lds) {
  __builtin_amdgcn_global_load_lds((const __attribute__((address_space(1))) u32*)g,
                                   (__attribute__((address_space(3))) u32*)lds, 16, 0, 0);
}

__global__ void e2_kernel(const float* __restrict__ emb, float* __restrict__ e2) {
  const int row  = blockIdx.x * 4 + (threadIdx.x >> 6);
  const int lane = threadIdx.x & 63;
  const float4 v = ((const float4*)(emb + (size_t)row * DDIM))[lane];
  float s = v.x * v.x + v.y * v.y + v.z * v.z + v.w * v.w;
  #pragma unroll
  for (int m = 32; m >= 1; m >>= 1) s += __shfl_xor(s, m);
  if (lane == 0) e2[row] = s;
}

// Pack eh into A-frag stream: slot t=((qi*16+w)*32+c)*64+l, c=(ekt*4+ci):
//   code = 64w+16ci+(l&15), k = 32ekt+8*(l>>4)+j  (8 bf16 per slot)
__global__ void pack_kernel(const float* __restrict__ emb, u16* __restrict__ packE) {
  const int t  = blockIdx.x * 256 + threadIdx.x;   // 262144 slots
  const int l  = t & 63;
  const int c  = (t >> 6) & 31;
  const int w  = (t >> 11) & 15;
  const int qi = t >> 15;
  const int code = 64 * w + 16 * (c & 3) + (l & 15);
  const int k    = 32 * (c >> 2) + 8 * (l >> 4);
  const float* src = emb + ((size_t)qi * KC + code) * DDIM + k;
  short8 v;
  #pragma unroll
  for (int j = 0; j < 8; ++j) v[j] = (short)f2bf(src[j]);
  *(short8*)(packE + (size_t)t * 8) = v;
}

__global__ __launch_bounds__(1024)
void rvq_kernel(const float* __restrict__ x, const float* __restrict__ emb,
                const char* __restrict__ packEb, const float* __restrict__ e2g,
                float* __restrict__ out, float* __restrict__ outIdx,
                float* __restrict__ lossPart)
{
  __shared__ __align__(16) u16  Rh[BR * 256];      // 32KB rh residual (swizzled)
  __shared__ __align__(16) char Bbuf[16][4][1024]; // 64KB per-wave A staging, 4-deep
  __shared__ float e2L[KC];                        // 4KB
  __shared__ float sredV[16][BR];                  // 4KB
  __shared__ int   sredI[16][BR];                  // 4KB
  __shared__ float d0L[BR];
  __shared__ int   cntL[BR];
  __shared__ int   candL[BR][MCAP];                // 6KB
  __shared__ int   sidx[BR];
  __shared__ float rnormL[BR];
  __shared__ float red[16];

  const int tid = threadIdx.x;
  const int w = tid >> 6, l = tid & 63;
  const int row = tid >> 4, sub = tid & 15;        // 64 rows x 16 threads
  const size_t rowBase = (size_t)blockIdx.x * BR;
  char* RhB = (char*)Rh;
  float lossAcc = 0.f;
  float r[16];                                     // f32 residual, d = 16*sub + i

  // ---- init: r = x slice; write rh to LDS; rnorm ----
  {
    const float* xp = x + (rowBase + row) * DDIM + 16 * sub;
    float rn = 0.f;
    #pragma unroll
    for (int f = 0; f < 4; ++f) {
      f32x4 v = *(const f32x4*)(xp + 4 * f);
      r[4*f+0] = v.x; r[4*f+1] = v.y; r[4*f+2] = v.z; r[4*f+3] = v.w;
      rn += v.x*v.x + v.y*v.y + v.z*v.z + v.w*v.w;
    }
    short8 h0, h1;
    #pragma unroll
    for (int j = 0; j < 8; ++j) { h0[j] = (short)f2bf(r[j]); h1[j] = (short)f2bf(r[8+j]); }
    *(short8*)(RhB + runit(row, 2*sub))     = h0;
    *(short8*)(RhB + runit(row, 2*sub + 1)) = h1;
    rn += __shfl_xor(rn, 1); rn += __shfl_xor(rn, 2);
    rn += __shfl_xor(rn, 4); rn += __shfl_xor(rn, 8);
    if (sub == 0) rnormL[row] = rn;
  }
  __syncthreads();

  for (int qi = 0; qi < QST; ++qi) {
    e2L[tid] = e2g[qi * KC + tid];

    // ---- GEMM: wave w covers codes [64w,64w+64) x all 64 rows, K=256 ----
    f32x4 acc[4][4];
    #pragma unroll
    for (int a = 0; a < 4; ++a)
      #pragma unroll
      for (int b = 0; b < 4; ++b) acc[a][b] = (f32x4){0.f, 0.f, 0.f, 0.f};

    const char* src = packEb + ((size_t)(qi * 16 + w) * 32) * 1024 + (size_t)l * 16;
    #define ISSUE(c) gld16(src + (size_t)(c) * 1024, &Bbuf[w][(c) & 3][0])
    ISSUE(0); ISSUE(1); ISSUE(2);
    for (int ekt = 0; ekt < 8; ++ekt) {
      short8 Bf[4];
      #pragma unroll
      for (int ri = 0; ri < 4; ++ri)
        Bf[ri] = *(const short8*)(RhB + runit(16 * ri + (l & 15), ekt * 4 + (l >> 4)));
      #pragma unroll
      for (int ci = 0; ci < 4; ++ci) {
        const int c = ekt * 4 + ci;
        if (c < 29)      { ISSUE(c + 3); asm volatile("s_waitcnt vmcnt(3)" ::: "memory"); }
        else if (c == 29) asm volatile("s_waitcnt vmcnt(2)" ::: "memory");
        else if (c == 30) asm volatile("s_waitcnt vmcnt(1)" ::: "memory");
        else              asm volatile("s_waitcnt vmcnt(0)" ::: "memory");
        const short8 Af = *(const short8*)(&Bbuf[w][c & 3][l * 16]);
        #pragma unroll
        for (int ri = 0; ri < 4; ++ri)
          acc[ci][ri] = __builtin_amdgcn_mfma_f32_16x16x32_bf16(Af, Bf[ri], acc[ci][ri], 0, 0, 0);
      }
    }
    #undef ISSUE
    __syncthreads();   // e2L visible; all waves done reading Rh

    // ---- scoring + wave-local argmin ----
    float bestV[4]; int bestI[4];
    #pragma unroll
    for (int ri = 0; ri < 4; ++ri) { bestV[ri] = 3.4e38f; bestI[ri] = 0; }
    #pragma unroll
    for (int ci = 0; ci < 4; ++ci) {
      const int cb = 64 * w + 16 * ci + 4 * (l >> 4);
      f32x4 e4 = *(const f32x4*)&e2L[cb];
      #pragma unroll
      for (int jj = 0; jj < 4; ++jj) {
        #pragma unroll
        for (int ri = 0; ri < 4; ++ri) {
          float d = e4[jj] - 2.f * acc[ci][ri][jj];
          if (d < bestV[ri]) { bestV[ri] = d; bestI[ri] = cb + jj; }
        }
      }
    }
    #pragma unroll
    for (int m = 16; m <= 32; m <<= 1) {
      #pragma unroll
      for (int ri = 0; ri < 4; ++ri) {
        float ov = __shfl_xor(bestV[ri], m);
        int   oi = __shfl_xor(bestI[ri], m);
        if (ov < bestV[ri] || (ov == bestV[ri] && oi < bestI[ri])) { bestV[ri] = ov; bestI[ri] = oi; }
      }
    }
    if (l < 16) {
      #pragma unroll
      for (int ri = 0; ri < 4; ++ri) { sredV[w][16*ri + l] = bestV[ri]; sredI[w][16*ri + l] = bestI[ri]; }
    }
    __syncthreads();

    // ---- cross-wave min, provisional idx, reset counters ----
    if (tid < BR) {
      float dv = sredV[0][tid]; int di = sredI[0][tid];
      #pragma unroll
      for (int wv = 1; wv < 16; ++wv) {
        float v = sredV[wv][tid]; int ii = sredI[wv][tid];
        if (v < dv || (v == dv && ii < di)) { dv = v; di = ii; }
      }
      d0L[tid] = dv; sidx[tid] = di; cntL[tid] = 0;
    }
    __syncthreads();

    // ---- candidates within guaranteed margin ----
    {
      float thr[4];
      #pragma unroll
      for (int ri = 0; ri < 4; ++ri) {
        const int rw = 16 * ri + (l & 15);
        thr[ri] = d0L[rw] + 0.36f * sqrtf(rnormL[rw]) + 0.05f;
      }
      #pragma unroll
      for (int ci = 0; ci < 4; ++ci) {
        const int cb = 64 * w + 16 * ci + 4 * (l >> 4);
        f32x4 e4 = *(const f32x4*)&e2L[cb];
        #pragma unroll
        for (int jj = 0; jj < 4; ++jj) {
          #pragma unroll
          for (int ri = 0; ri < 4; ++ri) {
            float d = e4[jj] - 2.f * acc[ci][ri][jj];
            if (d <= thr[ri]) {
              const int rw = 16 * ri + (l & 15);
              int p = atomicAdd(&cntL[rw], 1);
              if (p < MCAP) candL[rw][p] = cb + jj;
            }
          }
        }
      }
    }
    __syncthreads();

    // ---- exact f32 rescue for contested rows (16 thr/row) ----
    {
      int cnt = cntL[row];
      if (cnt > 1) {
        float bd = 3.4e38f; int bi = 0x7fffffff;
        const int n = (cnt <= MCAP) ? cnt : KC;    // overflow -> full exact scan
        for (int k2 = 0; k2 < n; ++k2) {
          const int c = (cnt <= MCAP) ? candL[row][k2] : k2;
          const float* ep = emb + ((size_t)qi * KC + c) * DDIM + 16 * sub;
          float dot = 0.f;
          #pragma unroll
          for (int f = 0; f < 4; ++f) {
            f32x4 ev = *(const f32x4*)(ep + 4 * f);
            dot += r[4*f+0]*ev.x + r[4*f+1]*ev.y + r[4*f+2]*ev.z + r[4*f+3]*ev.w;
          }
          dot += __shfl_xor(dot, 1); dot += __shfl_xor(dot, 2);
          dot += __shfl_xor(dot, 4); dot += __shfl_xor(dot, 8);
          float d = e2L[c] - 2.f * dot;
          if (d < bd || (d == bd && c < bi)) { bd = d; bi = c; }
        }
        if (sub == 0) sidx[row] = bi;
      }
    }
    __syncthreads();

    // ---- residual update (f32 regs), rewrite rh, loss, rnorm, indices ----
    {
      const int c = sidx[row];
      const float* ep = emb + ((size_t)qi * KC + c) * DDIM + 16 * sub;
      float ls = 0.f;
      #pragma unroll
      for (int f = 0; f < 4; ++f) {
        f32x4 ev = *(const f32x4*)(ep + 4 * f);
        r[4*f+0] -= ev.x; ls += r[4*f+0]*r[4*f+0];
        r[4*f+1] -= ev.y; ls += r[4*f+1]*r[4*f+1];
        r[4*f+2] -= ev.z; ls += r[4*f+2]*r[4*f+2];
        r[4*f+3] -= ev.w; ls += r[4*f+3]*r[4*f+3];
      }
      short8 h0, h1;
      #pragma unroll
      for (int j = 0; j < 8; ++j) { h0[j] = (short)f2bf(r[j]); h1[j] = (short)f2bf(r[8+j]); }
      *(short8*)(RhB + runit(row, 2*sub))     = h0;
      *(short8*)(RhB + runit(row, 2*sub + 1)) = h1;
      lossAcc += ls;
      float rn = ls;
      rn += __shfl_xor(rn, 1); rn += __shfl_xor(rn, 2);
      rn += __shfl_xor(rn, 4); rn += __shfl_xor(rn, 8);
      if (sub == 0) rnormL[row] = rn;
      if (tid < BR) outIdx[(rowBase + tid) * QST + qi] = (float)sidx[tid];
    }
    __syncthreads();
  }

  // ---- final: out = x - r_final ----
  {
    const float* xp = x + (rowBase + row) * DDIM + 16 * sub;
    float* op = out + (rowBase + row) * DDIM + 16 * sub;
    #pragma unroll
    for (int f = 0; f < 4; ++f) {
      f32x4 xv = *(const f32x4*)(xp + 4 * f);
      f32x4 o;
      o.x = xv.x - r[4*f+0]; o.y = xv.y - r[4*f+1];
      o.z = xv.z - r[4*f+2]; o.w = xv.w - r[4*f+3];
      *(f32x4*)(op + 4 * f) = o;
    }
  }

  // ---- deterministic per-block loss partial ----
  {
    float s = lossAcc;
    #pragma unroll
    for (int m = 32; m >= 1; m >>= 1) s += __shfl_xor(s, m);
    if (l == 0) red[w] = s;
    __syncthreads();
    if (tid == 0) {
      float t2 = 0.f;
      #pragma unroll
      for (int wv = 0; wv < 16; ++wv) t2 += red[wv];
      lossPart[blockIdx.x] = t2;
    }
  }
}

__global__ void loss_final(const float* __restrict__ part, float* __restrict__ outLoss) {
  __shared__ float buf[256];
  const int t = threadIdx.x;
  float s = 0.f;
  #pragma unroll
  for (int k = 0; k < 4; ++k) s += part[t + 256 * k];
  buf[t] = s;
  __syncthreads();
  for (int st = 128; st >= 1; st >>= 1) {
    if (t < st) buf[t] += buf[t + st];
    __syncthreads();
  }
  if (t == 0) *outLoss = buf[0] * (1.25f / 16777216.f);
}

extern "C" void kernel_launch(void* const* d_in, const int* in_sizes, int n_in,
                              void* d_out, int out_size, void* d_ws, size_t ws_size,
                              hipStream_t stream) {
  (void)in_sizes; (void)n_in; (void)out_size; (void)ws_size;
  const float* x   = (const float*)d_in[0];
  const float* emb = (const float*)d_in[1];
  float* out     = (float*)d_out;
  float* outLoss = out + (size_t)NROWS * DDIM;            // 16777216
  float* outIdx  = outLoss + 1;                           // indices as float
  char*  packE   = (char*)d_ws;                           // 4 MB bf16 A-frag stream
  float* e2      = (float*)(packE + (size_t)QST * 16 * 32 * 1024);  // 8192 f32
  float* part    = e2 + QST * KC;                         // 1024 f32

  pack_kernel<<<dim3(1024), dim3(256), 0, stream>>>(emb, (u16*)packE);
  e2_kernel<<<dim3(QST * KC / 4), dim3(256), 0, stream>>>(emb, e2);
  rvq_kernel<<<dim3(NROWS / BR), dim3(1024), 0, stream>>>(x, emb, packE, e2, out, outIdx, part);
  loss_final<<<dim3(1), dim3(256), 0, stream>>>(part, outLoss);
}